// Round 7
// baseline (245.502 us; speedup 1.0000x reference)
//
#include <hip/hip_runtime.h>

// ---------------------------------------------------------------------------
// CrossModeAttention: B=4, N=1024, D1=D2=512, C=512, H=8, DH=64, LAYERS=3
// Q,K layer-invariant => P = exp(QK^T*scale) computed ONCE (bf16, linear,
// 64MB, L3-resident); each layer = P·V GEMM (BK=128, prefetched) + fused
// LayerNorm(+transpose). Fallback fused flash-attn if ws < 103MB.
// ---------------------------------------------------------------------------

#define LOG2E 1.44269504088896f

using f32x4   = __attribute__((ext_vector_type(4))) float;
using short8  = __attribute__((ext_vector_type(8))) short;
using ushort8 = __attribute__((ext_vector_type(8))) unsigned short;

__device__ inline unsigned short f2bf(float f) {
  unsigned u = __builtin_bit_cast(unsigned, f);
  u += 0x7fffu + ((u >> 16) & 1u);   // RNE
  return (unsigned short)(u >> 16);
}

__device__ inline f32x4 mfma_bf16(short8 a, short8 b, f32x4 c) {
  return __builtin_amdgcn_mfma_f32_16x16x32_bf16(a, b, c, 0, 0, 0);
}

// async global->LDS, 16B per lane; LDS dest = wave-uniform base + lane*16
__device__ inline void gload_lds16(const void* g, void* l) {
  __builtin_amdgcn_global_load_lds(
      (const __attribute__((address_space(1))) unsigned int*)g,
      (__attribute__((address_space(3))) unsigned int*)l, 16, 0, 0);
}

// XOR swizzle for 128B-row LDS tiles (G4)
__device__ inline int swz(int row, int byte_in_row) {
  return row * 128 + (byte_in_row ^ ((row & 7) << 4));
}
// XOR swizzle for 256B-row LDS tiles: swizzle within each 128B half
__device__ inline int swz2(int row, int byte_in_row) {
  return row * 256 + (byte_in_row & 128) +
         ((byte_in_row & 127) ^ ((row & 7) << 4));
}

// ---------------------------------------------------------------------------
// Convert x1|x2 (f32) -> xb bf16 [4096][1024]
// ---------------------------------------------------------------------------
__global__ __launch_bounds__(256) void k_convert_x(
    const float* __restrict__ x1, const float* __restrict__ x2,
    unsigned short* __restrict__ xb) {
  int i  = blockIdx.x * 256 + threadIdx.x;
  int e0 = i * 8;
  int m  = e0 >> 10;
  int d  = e0 & 1023;
  const float* src = (d < 512) ? (x1 + (size_t)m * 512 + d)
                               : (x2 + (size_t)m * 512 + (d - 512));
  float4 a = ((const float4*)src)[0];
  float4 b = ((const float4*)src)[1];
  ushort8 o;
  o[0] = f2bf(a.x); o[1] = f2bf(a.y); o[2] = f2bf(a.z); o[3] = f2bf(a.w);
  o[4] = f2bf(b.x); o[5] = f2bf(b.y); o[6] = f2bf(b.z); o[7] = f2bf(b.w);
  *(ushort8*)(xb + (size_t)e0) = o;
}

// Generic f32 -> bf16 (weights)
__global__ __launch_bounds__(256) void k_convert(
    const float* __restrict__ in, unsigned short* __restrict__ out, int n8) {
  int i = blockIdx.x * 256 + threadIdx.x;
  if (i >= n8) return;
  const float4* p = (const float4*)(in + (size_t)i * 8);
  float4 a = p[0], b = p[1];
  ushort8 o;
  o[0] = f2bf(a.x); o[1] = f2bf(a.y); o[2] = f2bf(a.z); o[3] = f2bf(a.w);
  o[4] = f2bf(b.x); o[5] = f2bf(b.y); o[6] = f2bf(b.z); o[7] = f2bf(b.w);
  *(ushort8*)(out + (size_t)i * 8) = o;
}

// ---------------------------------------------------------------------------
// Projections: m97-structure GEMM. 128x128 tile, BK=64, global_load_lds.
// z=0 Q (K=512), z=1 K (K=512), z=2 V (K=1024).
// ---------------------------------------------------------------------------
__global__ __launch_bounds__(256) void k_proj(
    const unsigned short* __restrict__ xb,
    const unsigned short* __restrict__ Wqb,
    const unsigned short* __restrict__ Wkb,
    const unsigned short* __restrict__ Wvb,
    unsigned short* __restrict__ Qb, unsigned short* __restrict__ Kb,
    float* __restrict__ Vf) {
  __shared__ __align__(16) unsigned short Atile[128 * 64];
  __shared__ __align__(16) unsigned short Btile[128 * 64];

  const int id  = blockIdx.x;
  const int z   = id % 3;
  const int rem = id / 3;
  const int c0  = (rem & 3) * 128;
  const int m0  = (rem >> 2) * 128;

  const int K    = (z == 2) ? 1024 : 512;
  const int aoff = (z == 1) ? 512 : 0;
  const unsigned short* W = (z == 0) ? Wqb : (z == 1) ? Wkb : Wvb;

  const int t  = threadIdx.x;
  const int w  = t >> 6, l = t & 63;
  const int lr = l & 15, ls = l >> 4;
  const int wr = w >> 1, wc = w & 1;

  const int srow  = l >> 3;
  const int scol8 = (l & 7) * 8;

  f32x4 acc[4][4] = {};

  for (int k0 = 0; k0 < K; k0 += 64) {
#pragma unroll
    for (int j = 0; j < 4; ++j) {
      int ch  = w * 4 + j;
      int row = ch * 8 + srow;
      gload_lds16(xb + (size_t)(m0 + row) * 1024 + aoff + k0 + scol8,
                  Atile + ch * 512);
      gload_lds16(W + (size_t)(c0 + row) * K + k0 + scol8,
                  Btile + ch * 512);
    }
    __syncthreads();
#pragma unroll
    for (int ks = 0; ks < 2; ++ks) {
      short8 af[4], bf[4];
#pragma unroll
      for (int mf = 0; mf < 4; ++mf)
        af[mf] = *(const short8*)(Atile + (wr * 64 + mf * 16 + lr) * 64 +
                                  ks * 32 + ls * 8);
#pragma unroll
      for (int nf = 0; nf < 4; ++nf)
        bf[nf] = *(const short8*)(Btile + (wc * 64 + nf * 16 + lr) * 64 +
                                  ks * 32 + ls * 8);
#pragma unroll
      for (int mf = 0; mf < 4; ++mf)
#pragma unroll
        for (int nf = 0; nf < 4; ++nf)
          acc[mf][nf] = mfma_bf16(af[mf], bf[nf], acc[mf][nf]);
    }
    __syncthreads();
  }

#pragma unroll
  for (int mf = 0; mf < 4; ++mf)
#pragma unroll
    for (int nf = 0; nf < 4; ++nf)
#pragma unroll
      for (int r = 0; r < 4; ++r) {
        int m = m0 + wr * 64 + mf * 16 + ls * 4 + r;
        int c = c0 + wc * 64 + nf * 16 + lr;
        float v = acc[mf][nf][r];
        if (z == 2) {
          Vf[(size_t)m * 512 + c] = v;
        } else {
          int b = m >> 10, n = m & 1023, h = c >> 6, dh = c & 63;
          size_t idx = ((size_t)(b * 8 + h) * 1024 + n) * 64 + dh;
          (z == 0 ? Qb : Kb)[idx] = f2bf(v);
        }
      }
}

// ---------------------------------------------------------------------------
// Transpose (initial only): Vf f32 [B,N,512] -> Vt bf16 [B,H,64,N]
// ---------------------------------------------------------------------------
__global__ __launch_bounds__(256) void k_transpose_v(
    const float* __restrict__ Vf, unsigned short* __restrict__ Vt) {
  __shared__ unsigned short tile[64 * 66];
  const int bh = blockIdx.y;
  const int b = bh >> 3, h = bh & 7;
  const int n0 = blockIdx.x * 64;
  const int t = threadIdx.x;
  {
    int n = t >> 2, dh0 = (t & 3) * 16;
    const float* src = Vf + ((size_t)b * 1024 + n0 + n) * 512 + h * 64 + dh0;
    unsigned short* dst = tile + n * 66 + dh0;
#pragma unroll
    for (int j = 0; j < 16; j += 4) {
      float4 v = *(const float4*)(src + j);
      dst[j + 0] = f2bf(v.x); dst[j + 1] = f2bf(v.y);
      dst[j + 2] = f2bf(v.z); dst[j + 3] = f2bf(v.w);
    }
  }
  __syncthreads();
#pragma unroll
  for (int it = 0; it < 2; ++it) {
    int dh = (t >> 3) + it * 32, n8 = (t & 7) * 8;
    ushort8 o;
#pragma unroll
    for (int j = 0; j < 8; ++j) o[j] = tile[(n8 + j) * 66 + dh];
    *(ushort8*)(Vt + ((size_t)(bh * 64 + dh)) * 1024 + n0 + n8) = o;
  }
}

// ---------------------------------------------------------------------------
// k_scores: P = exp(QK^T*scale) (unnormalized, |s*scale|<~1), masked
// (s==0 -> 0). P bf16 [32][1024][1024] LINEAR row-major, coalesced 128B-row
// writes. Row sums -> lsum_g f32 [32][1024].
// ---------------------------------------------------------------------------
__global__ __launch_bounds__(256) void k_scores(
    const unsigned short* __restrict__ Qb,
    const unsigned short* __restrict__ Kb,
    unsigned short* __restrict__ Pmat, float* __restrict__ lsum_g) {
  __shared__ char lds[8192 + 4 * 16 * 144];
  char* kbuf = lds;
  const int bh = blockIdx.y;
  const int q0 = blockIdx.x * 64;
  const int t = threadIdx.x;
  const int w = t >> 6, l = t & 63, lr = l & 15, ls = l >> 4;
  char* pbuf = lds + 8192 + w * (16 * 144);

  const float sclog2e = 0.0637587160f;   // (512^-0.5) * log2(e)

  short8 qa[2];
  {
    const unsigned short* Qg =
        Qb + ((size_t)bh * 1024 + q0 + w * 16 + lr) * 64 + ls * 8;
    qa[0] = *(const short8*)(Qg);
    qa[1] = *(const short8*)(Qg + 32);
  }

  const unsigned short* Kg = Kb + (size_t)bh * 1024 * 64;
  unsigned short* Pg = Pmat + (size_t)bh * 1024 * 1024;

  float lacc[4] = {0.f, 0.f, 0.f, 0.f};

  const int srow = t >> 3, sc8 = (t & 7) * 8;
  int4 kreg[2];
  kreg[0] = *(const int4*)(Kg + (size_t)(srow)*64 + sc8);
  kreg[1] = *(const int4*)(Kg + (size_t)(srow + 32) * 64 + sc8);

  for (int kc = 0; kc < 16; ++kc) {
    *(int4*)(kbuf + swz(srow, sc8 * 2)) = kreg[0];
    *(int4*)(kbuf + swz(srow + 32, sc8 * 2)) = kreg[1];
    __syncthreads();
    if (kc < 15) {   // T14: issue next K-chunk loads before compute
      kreg[0] = *(const int4*)(Kg + (size_t)((kc + 1) * 64 + srow) * 64 + sc8);
      kreg[1] = *(const int4*)(Kg + (size_t)((kc + 1) * 64 + srow + 32) * 64 + sc8);
    }

    // S = Q K^T
    f32x4 s[4] = {};
#pragma unroll
    for (int kk = 0; kk < 2; ++kk) {
#pragma unroll
      for (int nt = 0; nt < 4; ++nt) {
        short8 bk = *(const short8*)(kbuf + swz(nt * 16 + lr, kk * 64 + ls * 16));
        s[nt] = mfma_bf16(qa[kk], bk, s[nt]);
      }
    }

    // p = exp(s*scale) masked; accumulate row sums; stage to pbuf
#pragma unroll
    for (int nt = 0; nt < 4; ++nt)
#pragma unroll
      for (int r = 0; r < 4; ++r) {
        float sv = s[nt][r];
        float pv = (sv == 0.f) ? 0.f : exp2f(sv * sclog2e);
        lacc[r] += pv;
        *(unsigned short*)(pbuf + (ls * 4 + r) * 144 + (nt * 16 + lr) * 2) =
            f2bf(pv);
      }

    // coalesced linear write: 8 lanes cover one full 128B row
#pragma unroll
    for (int half = 0; half < 2; ++half) {
      int flat = l + half * 64;          // 0..127
      int prow = flat >> 3;              // 0..15
      int pchk = flat & 7;               // 0..7
      ushort8 pv8 = *(const ushort8*)(pbuf + prow * 144 + pchk * 16);
      int n = q0 + w * 16 + prow;
      *(ushort8*)(Pg + (size_t)n * 1024 + kc * 64 + pchk * 8) = pv8;
    }
    __syncthreads();
  }

#pragma unroll
  for (int r = 0; r < 4; ++r) {
#pragma unroll
    for (int off = 1; off < 16; off <<= 1)
      lacc[r] += __shfl_xor(lacc[r], off, 64);
  }
  if (lr == 0) {
#pragma unroll
    for (int r = 0; r < 4; ++r)
      lsum_g[(size_t)bh * 1024 + q0 + w * 16 + ls * 4 + r] = lacc[r];
  }
}

// ---------------------------------------------------------------------------
// k_pv: V1[n, h*64+dh] = (1/l[n]) * sum_m P[n,m] * Vt[h][dh][m].
// BK=128, reg-staged A and B with swz2 ds_write, T14 issue-early prefetch.
// 64 n-rows per block, 4 waves x 16 rows.
// ---------------------------------------------------------------------------
__global__ __launch_bounds__(256) void k_pv(
    const unsigned short* __restrict__ Pmat,
    const unsigned short* __restrict__ Vt,
    const float* __restrict__ lsum_g, float* __restrict__ V1) {
  __shared__ __align__(16) char Atile[64 * 256];   // [64 n][128 m] swz2
  __shared__ __align__(16) char Btile[64 * 256];   // [64 dh][128 m] swz2
  const int head = blockIdx.y;
  const int n0 = blockIdx.x * 64;
  const int t = threadIdx.x;
  const int w = t >> 6, l = t & 63, lr = l & 15, ls = l >> 4;

  const unsigned short* Pg =
      Pmat + (size_t)head * 1024 * 1024 + (size_t)n0 * 1024;
  const unsigned short* Vg = Vt + (size_t)head * 64 * 1024;

  f32x4 acc[4] = {};
  int4 areg[4], vreg[4];

  // staging map: flat = t + it*256 in 0..1023; row = flat>>4 (0..63),
  // c16 = flat&15 -> 16 lanes cover a 256B row-segment contiguously.
#pragma unroll
  for (int it = 0; it < 4; ++it) {
    int flat = t + it * 256, row = flat >> 4, c16 = flat & 15;
    areg[it] = *(const int4*)(Pg + (size_t)row * 1024 + c16 * 8);
    vreg[it] = *(const int4*)(Vg + (size_t)row * 1024 + c16 * 8);
  }

  for (int kc = 0; kc < 8; ++kc) {
#pragma unroll
    for (int it = 0; it < 4; ++it) {
      int flat = t + it * 256, row = flat >> 4, c16 = flat & 15;
      *(int4*)(Atile + swz2(row, c16 * 16)) = areg[it];
      *(int4*)(Btile + swz2(row, c16 * 16)) = vreg[it];
    }
    __syncthreads();
    if (kc < 7) {   // T14: issue next chunk's loads; latency hides under MFMA
      int koff = (kc + 1) * 128;
#pragma unroll
      for (int it = 0; it < 4; ++it) {
        int flat = t + it * 256, row = flat >> 4, c16 = flat & 15;
        areg[it] = *(const int4*)(Pg + (size_t)row * 1024 + koff + c16 * 8);
        vreg[it] = *(const int4*)(Vg + (size_t)row * 1024 + koff + c16 * 8);
      }
    }
#pragma unroll
    for (int ks = 0; ks < 4; ++ks) {
      short8 af = *(const short8*)(Atile + swz2(w * 16 + lr, ks * 64 + ls * 16));
#pragma unroll
      for (int nf = 0; nf < 4; ++nf) {
        short8 bf =
            *(const short8*)(Btile + swz2(nf * 16 + lr, ks * 64 + ls * 16));
        acc[nf] = mfma_bf16(af, bf, acc[nf]);
      }
    }
    __syncthreads();
  }

  const int b = head >> 3, h = head & 7;
#pragma unroll
  for (int r = 0; r < 4; ++r) {
    int n = n0 + w * 16 + ls * 4 + r;
    float lv = lsum_g[(size_t)head * 1024 + n];
    float rinv = (lv > 0.f) ? 1.f / lv : 0.f;
#pragma unroll
    for (int nf = 0; nf < 4; ++nf)
      V1[((size_t)b * 1024 + n) * 512 + h * 64 + nf * 16 + lr] =
          acc[nf][r] * rinv;
  }
}

// ---------------------------------------------------------------------------
// Fused LayerNorm + transpose (layers 0/1): out_f32 = LN(V1+Vf) -> Vf_out,
// and bf16 transposed -> Vt. 16 rows per block (256 blocks).
// ---------------------------------------------------------------------------
__global__ __launch_bounds__(256) void k_ln_t(
    const float* __restrict__ V1, const float* __restrict__ Vf_in,
    const float* __restrict__ gamma, const float* __restrict__ beta,
    float* __restrict__ Vf_out, unsigned short* __restrict__ Vt) {
  __shared__ unsigned short tile[16 * 520];   // stride 520: conflict-free
  const int blk = blockIdx.x;
  const int b  = blk >> 6;
  const int n0 = (blk & 63) * 16;
  const int t = threadIdx.x;
  const int row = t >> 4;           // 0..15
  const int c0  = (t & 15) * 32;    // 32 cols per thread
  const size_t base = ((size_t)b * 1024 + n0 + row) * 512 + c0;

  float x[32];
  float s = 0.f, sq = 0.f;
#pragma unroll
  for (int j = 0; j < 32; j += 4) {
    float4 a = *(const float4*)(V1 + base + j);
    float4 v = *(const float4*)(Vf_in + base + j);
    float4 y = {a.x + v.x, a.y + v.y, a.z + v.z, a.w + v.w};
    x[j + 0] = y.x; x[j + 1] = y.y; x[j + 2] = y.z; x[j + 3] = y.w;
    s  += y.x + y.y + y.z + y.w;
    sq += y.x * y.x + y.y * y.y + y.z * y.z + y.w * y.w;
  }
#pragma unroll
  for (int off = 1; off < 16; off <<= 1) {
    s  += __shfl_xor(s, off, 64);
    sq += __shfl_xor(sq, off, 64);
  }
  float mu   = s * (1.f / 512.f);
  float var  = sq * (1.f / 512.f) - mu * mu;
  float rstd = rsqrtf(var + 1e-5f);

  unsigned short* trow = tile + row * 520 + c0;
#pragma unroll
  for (int j = 0; j < 32; j += 4) {
    float4 g = *(const float4*)(gamma + c0 + j);
    float4 bb = *(const float4*)(beta + c0 + j);
    float4 y;
    y.x = (x[j + 0] - mu) * rstd * g.x + bb.x;
    y.y = (x[j + 1] - mu) * rstd * g.y + bb.y;
    y.z = (x[j + 2] - mu) * rstd * g.z + bb.z;
    y.w = (x[j + 3] - mu) * rstd * g.w + bb.w;
    *(float4*)(Vf_out + base + j) = y;
    trow[j + 0] = f2bf(y.x); trow[j + 1] = f2bf(y.y);
    trow[j + 2] = f2bf(y.z); trow[j + 3] = f2bf(y.w);
  }
  __syncthreads();

#pragma unroll
  for (int it = 0; it < 2; ++it) {
    int d = t + it * 256;            // 0..511 (h*64+dh)
    int h = d >> 6, dh = d & 63;
    ushort8 o0, o1;
#pragma unroll
    for (int j = 0; j < 8; ++j) {
      o0[j] = tile[j * 520 + d];
      o1[j] = tile[(j + 8) * 520 + d];
    }
    unsigned short* dst = Vt + ((size_t)((b * 8 + h) * 64 + dh)) * 1024 + n0;
    *(ushort8*)(dst) = o0;
    *(ushort8*)(dst + 8) = o1;
  }
}

// ---------------------------------------------------------------------------
// Plain LayerNorm (final layer -> d_out)
// ---------------------------------------------------------------------------
__global__ __launch_bounds__(256) void k_ln(
    const float* __restrict__ V1, const float* __restrict__ Vf_in,
    const float* __restrict__ gamma, const float* __restrict__ beta,
    float* __restrict__ outp) {
  const int row = blockIdx.x;
  const int t = threadIdx.x;
  const float* a = V1 + (size_t)row * 512;
  const float* b = Vf_in + (size_t)row * 512;
  float x0 = a[t] + b[t];
  float x1 = a[t + 256] + b[t + 256];
  float s  = x0 + x1;
  float sq = x0 * x0 + x1 * x1;
#pragma unroll
  for (int off = 32; off >= 1; off >>= 1) {
    s  += __shfl_down(s, off, 64);
    sq += __shfl_down(sq, off, 64);
  }
  __shared__ float red[8];
  int w = t >> 6, l = t & 63;
  if (l == 0) { red[w] = s; red[w + 4] = sq; }
  __syncthreads();
  s  = red[0] + red[1] + red[2] + red[3];
  sq = red[4] + red[5] + red[6] + red[7];
  float mu   = s * (1.f / 512.f);
  float var  = sq * (1.f / 512.f) - mu * mu;
  float rstd = rsqrtf(var + 1e-5f);
  float y0 = (x0 - mu) * rstd * gamma[t] + beta[t];
  float y1 = (x1 - mu) * rstd * gamma[t + 256] + beta[t + 256];
  outp[(size_t)row * 512 + t] = y0;
  outp[(size_t)row * 512 + t + 256] = y1;
}

// ---------------------------------------------------------------------------
// Fallback fused flash attention (ws < 103MB only)
// ---------------------------------------------------------------------------
__global__ __launch_bounds__(256) void k_attn(
    const unsigned short* __restrict__ Qb,
    const unsigned short* __restrict__ Kb,
    const unsigned short* __restrict__ Vt,
    float* __restrict__ V1) {
  __shared__ char lds[8192 + 8192 + 4 * 16 * 144];
  char* kbuf = lds;
  char* vbuf = lds + 8192;
  const int bh = blockIdx.y;
  const int q0 = blockIdx.x * 64;
  const int t = threadIdx.x;
  const int w = t >> 6, l = t & 63, lr = l & 15, ls = l >> 4;
  char* pbuf = lds + 16384 + w * (16 * 144);

  const float scale = 0.044194173824159216f;

  short8 qa[2];
  {
    const unsigned short* Qg =
        Qb + ((size_t)bh * 1024 + q0 + w * 16 + lr) * 64 + ls * 8;
    qa[0] = *(const short8*)(Qg);
    qa[1] = *(const short8*)(Qg + 32);
  }

  f32x4 O[4] = {};
  float mrow[4], lrow[4];
#pragma unroll
  for (int r = 0; r < 4; ++r) { mrow[r] = -INFINITY; lrow[r] = 0.f; }

  const unsigned short* Kg = Kb + (size_t)bh * 1024 * 64;
  const unsigned short* Vg = Vt + (size_t)bh * 64 * 1024;

  for (int kc = 0; kc < 16; ++kc) {
    {
      int row = t >> 3;
      int c8  = (t & 7) * 8;
#pragma unroll
      for (int it = 0; it < 2; ++it) {
        int rr = row + it * 32;
        int4 kv = *(const int4*)(Kg + (size_t)(kc * 64 + rr) * 64 + c8);
        *(int4*)(kbuf + swz(rr, c8 * 2)) = kv;
        int4 vv = *(const int4*)(Vg + (size_t)rr * 1024 + kc * 64 + c8);
        *(int4*)(vbuf + swz(rr, c8 * 2)) = vv;
      }
    }
    __syncthreads();

    f32x4 s[4] = {};
#pragma unroll
    for (int kk = 0; kk < 2; ++kk) {
#pragma unroll
      for (int nt = 0; nt < 4; ++nt) {
        short8 bk = *(const short8*)(kbuf + swz(nt * 16 + lr, kk * 64 + ls * 16));
        s[nt] = mfma_bf16(qa[kk], bk, s[nt]);
      }
    }

    float p[4][4];
    float cmax[4];
#pragma unroll
    for (int r = 0; r < 4; ++r) cmax[r] = -INFINITY;
#pragma unroll
    for (int nt = 0; nt < 4; ++nt)
#pragma unroll
      for (int r = 0; r < 4; ++r) {
        float sv = s[nt][r];
        p[nt][r] = (sv == 0.f) ? -INFINITY : sv * scale;
        cmax[r] = fmaxf(cmax[r], p[nt][r]);
      }
#pragma unroll
    for (int r = 0; r < 4; ++r)
#pragma unroll
      for (int off = 1; off < 16; off <<= 1)
        cmax[r] = fmaxf(cmax[r], __shfl_xor(cmax[r], off, 64));

    float alpha[4];
#pragma unroll
    for (int r = 0; r < 4; ++r) {
      float mnew = fmaxf(mrow[r], cmax[r]);
      alpha[r] = (mnew == -INFINITY) ? 1.f : exp2f((mrow[r] - mnew) * LOG2E);
      mrow[r] = mnew;
    }
    float lsum[4] = {0.f, 0.f, 0.f, 0.f};
#pragma unroll
    for (int nt = 0; nt < 4; ++nt)
#pragma unroll
      for (int r = 0; r < 4; ++r) {
        float pv = (p[nt][r] == -INFINITY)
                       ? 0.f
                       : exp2f((p[nt][r] - mrow[r]) * LOG2E);
        p[nt][r] = pv;
        lsum[r] += pv;
      }
#pragma unroll
    for (int r = 0; r < 4; ++r) {
#pragma unroll
      for (int off = 1; off < 16; off <<= 1)
        lsum[r] += __shfl_xor(lsum[r], off, 64);
      lrow[r] = lrow[r] * alpha[r] + lsum[r];
    }
#pragma unroll
    for (int dt = 0; dt < 4; ++dt)
#pragma unroll
      for (int r = 0; r < 4; ++r) O[dt][r] *= alpha[r];

#pragma unroll
    for (int nt = 0; nt < 4; ++nt)
#pragma unroll
      for (int r = 0; r < 4; ++r)
        *(unsigned short*)(pbuf + (ls * 4 + r) * 144 + (nt * 16 + lr) * 2) =
            f2bf(p[nt][r]);

#pragma unroll
    for (int kk = 0; kk < 2; ++kk) {
      short8 pa = *(const short8*)(pbuf + lr * 144 + kk * 64 + ls * 16);
#pragma unroll
      for (int dt = 0; dt < 4; ++dt) {
        short8 bv = *(const short8*)(vbuf + swz(dt * 16 + lr, kk * 64 + ls * 16));
        O[dt] = mfma_bf16(pa, bv, O[dt]);
      }
    }
    __syncthreads();
  }

  float rinv[4];
#pragma unroll
  for (int r = 0; r < 4; ++r) rinv[r] = (lrow[r] > 0.f) ? 1.f / lrow[r] : 0.f;
  const int b = bh >> 3, h = bh & 7;
#pragma unroll
  for (int dt = 0; dt < 4; ++dt)
#pragma unroll
    for (int r = 0; r < 4; ++r) {
      int n = q0 + w * 16 + ls * 4 + r;
      int c = h * 64 + dt * 16 + lr;
      V1[((size_t)b * 1024 + n) * 512 + c] = O[dt][r] * rinv[r];
    }
}

// ---------------------------------------------------------------------------
extern "C" void kernel_launch(void* const* d_in, const int* in_sizes, int n_in,
                              void* d_out, int out_size, void* d_ws,
                              size_t ws_size, hipStream_t stream) {
  const float* x1    = (const float*)d_in[0];
  const float* x2    = (const float*)d_in[1];
  const float* Wq    = (const float*)d_in[2];
  const float* Wk    = (const float*)d_in[3];
  const float* Wv    = (const float*)d_in[4];
  const float* gamma = (const float*)d_in[5];
  const float* beta  = (const float*)d_in[6];
  float* out = (float*)d_out;
  char* ws = (char*)d_ws;

  const size_t MB = 1u << 20;
  unsigned short* xb  = (unsigned short*)(ws);                 // 8 MB
  unsigned short* Wqb = (unsigned short*)(ws + 8 * MB);        // 0.5 MB
  unsigned short* Wkb = (unsigned short*)(ws + 8 * MB + 512 * 1024);
  unsigned short* Wvb = (unsigned short*)(ws + 9 * MB);        // 1 MB
  unsigned short* Qb  = (unsigned short*)(ws + 10 * MB);       // 4 MB
  unsigned short* Kb  = (unsigned short*)(ws + 14 * MB);       // 4 MB
  unsigned short* Vt  = (unsigned short*)(ws + 18 * MB);       // 4 MB
  float*          Vf  = (float*)(ws + 22 * MB);                // 8 MB
  float*          V1  = (float*)(ws + 30 * MB);                // 8 MB
  float*          lsm = (float*)(ws + 38 * MB);                // 128 KB
  unsigned short* Pm  = (unsigned short*)(ws + 39 * MB);       // 64 MB

  const bool bigws = ws_size >= (size_t)103 * MB;

  k_convert_x<<<2048, 256, 0, stream>>>(x1, x2, xb);
  k_convert<<<128, 256, 0, stream>>>(Wq, Wqb, 32768);
  k_convert<<<128, 256, 0, stream>>>(Wk, Wkb, 32768);
  k_convert<<<256, 256, 0, stream>>>(Wv, Wvb, 65536);

  k_proj<<<384, 256, 0, stream>>>(xb, Wqb, Wkb, Wvb, Qb, Kb, Vf);
  k_transpose_v<<<dim3(16, 32), 256, 0, stream>>>(Vf, Vt);

  if (bigws) {
    k_scores<<<dim3(16, 32), 256, 0, stream>>>(Qb, Kb, Pm, lsm);
    for (int layer = 0; layer < 3; ++layer) {
      k_pv<<<dim3(16, 32), 256, 0, stream>>>(Pm, Vt, lsm, V1);
      if (layer < 2)
        k_ln_t<<<256, 256, 0, stream>>>(V1, Vf, gamma, beta, Vf, Vt);
      else
        k_ln<<<4096, 256, 0, stream>>>(V1, Vf, gamma, beta, out);
    }
  } else {
    for (int layer = 0; layer < 3; ++layer) {
      k_attn<<<dim3(16, 32), 256, 0, stream>>>(Qb, Kb, Vt, V1);
      if (layer < 2) {
        k_ln_t<<<256, 256, 0, stream>>>(V1, Vf, gamma, beta, Vf, Vt);
      } else {
        k_ln<<<4096, 256, 0, stream>>>(V1, Vf, gamma, beta, out);
      }
    }
  }
}

// Round 8
// 167.409 us; speedup vs baseline: 1.4665x; 1.4665x over previous
//
#include <hip/hip_runtime.h>

// ---------------------------------------------------------------------------
// CrossModeAttention: B=4, N=1024, D1=D2=512, C=512, H=8, DH=64, LAYERS=3
// Q,K layer-invariant => P = exp(QK^T*scale) computed ONCE (bf16, 64MB,
// PRE-SWIZZLED in-block, coalesced writes); each layer = P·V GEMM (2-phase
// double-buffered gload_lds) + fused LayerNorm(+swizzled transpose).
// ---------------------------------------------------------------------------

#define LOG2E 1.44269504088896f

using f32x4   = __attribute__((ext_vector_type(4))) float;
using short8  = __attribute__((ext_vector_type(8))) short;
using ushort8 = __attribute__((ext_vector_type(8))) unsigned short;

__device__ inline unsigned short f2bf(float f) {
  unsigned u = __builtin_bit_cast(unsigned, f);
  u += 0x7fffu + ((u >> 16) & 1u);   // RNE
  return (unsigned short)(u >> 16);
}

__device__ inline f32x4 mfma_bf16(short8 a, short8 b, f32x4 c) {
  return __builtin_amdgcn_mfma_f32_16x16x32_bf16(a, b, c, 0, 0, 0);
}

// async global->LDS, 16B per lane; LDS dest = wave-uniform base + lane*16
__device__ inline void gload_lds16(const void* g, void* l) {
  __builtin_amdgcn_global_load_lds(
      (const __attribute__((address_space(1))) unsigned int*)g,
      (__attribute__((address_space(3))) unsigned int*)l, 16, 0, 0);
}

// XOR swizzle for 128B-row LDS tiles (G4)
__device__ inline int swz(int row, int byte_in_row) {
  return row * 128 + (byte_in_row ^ ((row & 7) << 4));
}

// ---------------------------------------------------------------------------
// Convert x1|x2 (f32) -> xb bf16 [4096][1024]
// ---------------------------------------------------------------------------
__global__ __launch_bounds__(256) void k_convert_x(
    const float* __restrict__ x1, const float* __restrict__ x2,
    unsigned short* __restrict__ xb) {
  int i  = blockIdx.x * 256 + threadIdx.x;
  int e0 = i * 8;
  int m  = e0 >> 10;
  int d  = e0 & 1023;
  const float* src = (d < 512) ? (x1 + (size_t)m * 512 + d)
                               : (x2 + (size_t)m * 512 + (d - 512));
  float4 a = ((const float4*)src)[0];
  float4 b = ((const float4*)src)[1];
  ushort8 o;
  o[0] = f2bf(a.x); o[1] = f2bf(a.y); o[2] = f2bf(a.z); o[3] = f2bf(a.w);
  o[4] = f2bf(b.x); o[5] = f2bf(b.y); o[6] = f2bf(b.z); o[7] = f2bf(b.w);
  *(ushort8*)(xb + (size_t)e0) = o;
}

// Generic f32 -> bf16 (weights)
__global__ __launch_bounds__(256) void k_convert(
    const float* __restrict__ in, unsigned short* __restrict__ out, int n8) {
  int i = blockIdx.x * 256 + threadIdx.x;
  if (i >= n8) return;
  const float4* p = (const float4*)(in + (size_t)i * 8);
  float4 a = p[0], b = p[1];
  ushort8 o;
  o[0] = f2bf(a.x); o[1] = f2bf(a.y); o[2] = f2bf(a.z); o[3] = f2bf(a.w);
  o[4] = f2bf(b.x); o[5] = f2bf(b.y); o[6] = f2bf(b.z); o[7] = f2bf(b.w);
  *(ushort8*)(out + (size_t)i * 8) = o;
}

// ---------------------------------------------------------------------------
// Projections: m97-structure GEMM. 128x128 tile, BK=64, global_load_lds.
// z=0 Q (K=512), z=1 K (K=512), z=2 V (K=1024).
// ---------------------------------------------------------------------------
__global__ __launch_bounds__(256) void k_proj(
    const unsigned short* __restrict__ xb,
    const unsigned short* __restrict__ Wqb,
    const unsigned short* __restrict__ Wkb,
    const unsigned short* __restrict__ Wvb,
    unsigned short* __restrict__ Qb, unsigned short* __restrict__ Kb,
    float* __restrict__ Vf) {
  __shared__ __align__(16) unsigned short Atile[128 * 64];
  __shared__ __align__(16) unsigned short Btile[128 * 64];

  const int id  = blockIdx.x;
  const int z   = id % 3;
  const int rem = id / 3;
  const int c0  = (rem & 3) * 128;
  const int m0  = (rem >> 2) * 128;

  const int K    = (z == 2) ? 1024 : 512;
  const int aoff = (z == 1) ? 512 : 0;
  const unsigned short* W = (z == 0) ? Wqb : (z == 1) ? Wkb : Wvb;

  const int t  = threadIdx.x;
  const int w  = t >> 6, l = t & 63;
  const int lr = l & 15, ls = l >> 4;
  const int wr = w >> 1, wc = w & 1;

  const int srow  = l >> 3;
  const int scol8 = (l & 7) * 8;

  f32x4 acc[4][4] = {};

  for (int k0 = 0; k0 < K; k0 += 64) {
#pragma unroll
    for (int j = 0; j < 4; ++j) {
      int ch  = w * 4 + j;
      int row = ch * 8 + srow;
      gload_lds16(xb + (size_t)(m0 + row) * 1024 + aoff + k0 + scol8,
                  Atile + ch * 512);
      gload_lds16(W + (size_t)(c0 + row) * K + k0 + scol8,
                  Btile + ch * 512);
    }
    __syncthreads();
#pragma unroll
    for (int ks = 0; ks < 2; ++ks) {
      short8 af[4], bf[4];
#pragma unroll
      for (int mf = 0; mf < 4; ++mf)
        af[mf] = *(const short8*)(Atile + (wr * 64 + mf * 16 + lr) * 64 +
                                  ks * 32 + ls * 8);
#pragma unroll
      for (int nf = 0; nf < 4; ++nf)
        bf[nf] = *(const short8*)(Btile + (wc * 64 + nf * 16 + lr) * 64 +
                                  ks * 32 + ls * 8);
#pragma unroll
      for (int mf = 0; mf < 4; ++mf)
#pragma unroll
        for (int nf = 0; nf < 4; ++nf)
          acc[mf][nf] = mfma_bf16(af[mf], bf[nf], acc[mf][nf]);
    }
    __syncthreads();
  }

#pragma unroll
  for (int mf = 0; mf < 4; ++mf)
#pragma unroll
    for (int nf = 0; nf < 4; ++nf)
#pragma unroll
      for (int r = 0; r < 4; ++r) {
        int m = m0 + wr * 64 + mf * 16 + ls * 4 + r;
        int c = c0 + wc * 64 + nf * 16 + lr;
        float v = acc[mf][nf][r];
        if (z == 2) {
          Vf[(size_t)m * 512 + c] = v;
        } else {
          int b = m >> 10, n = m & 1023, h = c >> 6, dh = c & 63;
          size_t idx = ((size_t)(b * 8 + h) * 1024 + n) * 64 + dh;
          (z == 0 ? Qb : Kb)[idx] = f2bf(v);
        }
      }
}

// ---------------------------------------------------------------------------
// Transpose (initial): Vf f32 [B,N,512] -> Vt bf16 [B,H,64,N], SWIZZLED
// in-block: byte ^= (dh&7)<<4 within each 128B n-segment.
// ---------------------------------------------------------------------------
__global__ __launch_bounds__(256) void k_transpose_v(
    const float* __restrict__ Vf, unsigned short* __restrict__ Vt) {
  __shared__ unsigned short tile[64 * 66];
  const int bh = blockIdx.y;
  const int b = bh >> 3, h = bh & 7;
  const int n0 = blockIdx.x * 64;
  const int t = threadIdx.x;
  {
    int n = t >> 2, dh0 = (t & 3) * 16;
    const float* src = Vf + ((size_t)b * 1024 + n0 + n) * 512 + h * 64 + dh0;
    unsigned short* dst = tile + n * 66 + dh0;
#pragma unroll
    for (int j = 0; j < 16; j += 4) {
      float4 v = *(const float4*)(src + j);
      dst[j + 0] = f2bf(v.x); dst[j + 1] = f2bf(v.y);
      dst[j + 2] = f2bf(v.z); dst[j + 3] = f2bf(v.w);
    }
  }
  __syncthreads();
#pragma unroll
  for (int it = 0; it < 2; ++it) {
    int dh = (t >> 3) + it * 32, n8 = (t & 7) * 8;
    ushort8 o;
#pragma unroll
    for (int j = 0; j < 8; ++j) o[j] = tile[(n8 + j) * 66 + dh];
    char* dst = (char*)Vt + ((size_t)(bh * 64 + dh)) * 2048 + n0 * 2 +
                ((n8 * 2) ^ ((dh & 7) << 4));
    *(ushort8*)dst = o;
  }
}

// ---------------------------------------------------------------------------
// k_scores: P = exp(QK^T*scale) (unnormalized, |s*scale|<~1), masked
// (s==0 -> 0). P bf16 [32][1024][1024], swizzled WITHIN each 128B block
// (byte ^= (n&7)<<4) but written as full coalesced 128B segments.
// Row sums -> lsum_g f32 [32][1024]. Grid 512 linear, XCD-chunked.
// ---------------------------------------------------------------------------
__global__ __launch_bounds__(256) void k_scores(
    const unsigned short* __restrict__ Qb,
    const unsigned short* __restrict__ Kb,
    unsigned short* __restrict__ Pmat, float* __restrict__ lsum_g) {
  __shared__ char lds[8192 + 4 * 16 * 144];
  char* kbuf = lds;
  const int id  = blockIdx.x;
  const int lid = (id & 7) * 64 + (id >> 3);   // head resident per XCD
  const int bh  = lid >> 4;
  const int q0  = (lid & 15) * 64;
  const int t = threadIdx.x;
  const int w = t >> 6, l = t & 63, lr = l & 15, ls = l >> 4;
  char* pbuf = lds + 8192 + w * (16 * 144);

  const float sclog2e = 0.0637587160f;   // (512^-0.5) * log2(e)

  short8 qa[2];
  {
    const unsigned short* Qg =
        Qb + ((size_t)bh * 1024 + q0 + w * 16 + lr) * 64 + ls * 8;
    qa[0] = *(const short8*)(Qg);
    qa[1] = *(const short8*)(Qg + 32);
  }

  const unsigned short* Kg = Kb + (size_t)bh * 1024 * 64;
  char* Pg = (char*)(Pmat + (size_t)bh * 1024 * 1024);

  float lacc[4] = {0.f, 0.f, 0.f, 0.f};

  const int srow = t >> 3, sc8 = (t & 7) * 8;
  int4 kreg[2];
  kreg[0] = *(const int4*)(Kg + (size_t)(srow)*64 + sc8);
  kreg[1] = *(const int4*)(Kg + (size_t)(srow + 32) * 64 + sc8);

  for (int kc = 0; kc < 16; ++kc) {
    *(int4*)(kbuf + swz(srow, sc8 * 2)) = kreg[0];
    *(int4*)(kbuf + swz(srow + 32, sc8 * 2)) = kreg[1];
    __syncthreads();
    if (kc < 15) {   // T14: issue next K-chunk loads before compute
      kreg[0] = *(const int4*)(Kg + (size_t)((kc + 1) * 64 + srow) * 64 + sc8);
      kreg[1] = *(const int4*)(Kg + (size_t)((kc + 1) * 64 + srow + 32) * 64 + sc8);
    }

    // S = Q K^T
    f32x4 s[4] = {};
#pragma unroll
    for (int kk = 0; kk < 2; ++kk) {
#pragma unroll
      for (int nt = 0; nt < 4; ++nt) {
        short8 bk = *(const short8*)(kbuf + swz(nt * 16 + lr, kk * 64 + ls * 16));
        s[nt] = mfma_bf16(qa[kk], bk, s[nt]);
      }
    }

    // p = exp(s*scale) masked; accumulate row sums; stage to pbuf
#pragma unroll
    for (int nt = 0; nt < 4; ++nt)
#pragma unroll
      for (int r = 0; r < 4; ++r) {
        float sv = s[nt][r];
        float pv = (sv == 0.f) ? 0.f : exp2f(sv * sclog2e);
        lacc[r] += pv;
        *(unsigned short*)(pbuf + (ls * 4 + r) * 144 + (nt * 16 + lr) * 2) =
            f2bf(pv);
      }

    // coalesced swizzled write: 8 lanes cover one full 128B row segment,
    // sub-chunk position permuted in-block (pchk*16 ^ (n&7)<<4).
#pragma unroll
    for (int half = 0; half < 2; ++half) {
      int flat = l + half * 64;          // 0..127
      int prow = flat >> 3;              // 0..15
      int pchk = flat & 7;               // 0..7
      ushort8 pv8 = *(const ushort8*)(pbuf + prow * 144 + pchk * 16);
      int n = q0 + w * 16 + prow;
      *(ushort8*)(Pg + (size_t)n * 2048 + kc * 128 +
                  ((pchk * 16) ^ ((n & 7) << 4))) = pv8;
    }
    __syncthreads();
  }

#pragma unroll
  for (int r = 0; r < 4; ++r) {
#pragma unroll
    for (int off = 1; off < 16; off <<= 1)
      lacc[r] += __shfl_xor(lacc[r], off, 64);
  }
  if (lr == 0) {
#pragma unroll
    for (int r = 0; r < 4; ++r)
      lsum_g[(size_t)bh * 1024 + q0 + w * 16 + ls * 4 + r] = lacc[r];
  }
}

// ---------------------------------------------------------------------------
// k_pv v3: V1[n, h*64+dh] = (1/l[n]) * sum_m P[n,m] * Vt[h][dh][m].
// Both A (P) and B (Vt) pre-swizzled in global -> pure gload_lds staging,
// DOUBLE-BUFFERED 2-phase (stage k+1 before compute k, one barrier/iter).
// Grid 512 linear, XCD-chunked so each head stays on one XCD (Vt L2-hot).
// ---------------------------------------------------------------------------
__global__ __launch_bounds__(256) void k_pv(
    const unsigned short* __restrict__ Pmat,
    const unsigned short* __restrict__ Vt,
    const float* __restrict__ lsum_g, float* __restrict__ V1) {
  __shared__ __align__(16) char Ab[2][8192];
  __shared__ __align__(16) char Bb[2][8192];
  const int id  = blockIdx.x;
  const int lid = (id & 7) * 64 + (id >> 3);
  const int head = lid >> 4;
  const int n0   = (lid & 15) * 64;
  const int t = threadIdx.x;
  const int w = t >> 6, l = t & 63, lr = l & 15, ls = l >> 4;

  const char* Pg =
      (const char*)(Pmat + (size_t)head * 1024 * 1024) + (size_t)n0 * 2048;
  const char* Vg = (const char*)(Vt + (size_t)head * 64 * 1024);

  const int srow = w * 16 + (l >> 3);   // + j*8
  const int sc16 = (l & 7) * 16;

  f32x4 acc[4] = {};

  auto STAGE = [&](int buf, int kc) {
#pragma unroll
    for (int j = 0; j < 2; ++j) {
      int row = srow + j * 8;
      gload_lds16(Pg + (size_t)row * 2048 + kc * 128 + sc16,
                  &Ab[buf][w * 2048 + j * 1024]);
      gload_lds16(Vg + (size_t)row * 2048 + kc * 128 + sc16,
                  &Bb[buf][w * 2048 + j * 1024]);
    }
  };

  STAGE(0, 0);
  __syncthreads();
  int cur = 0;
  for (int kc = 0; kc < 16; ++kc) {
    if (kc < 15) STAGE(cur ^ 1, kc + 1);   // loads fly under compute
#pragma unroll
    for (int ks = 0; ks < 2; ++ks) {
      short8 af = *(const short8*)(&Ab[cur][swz(w * 16 + lr, ks * 64 + ls * 16)]);
#pragma unroll
      for (int nf = 0; nf < 4; ++nf) {
        short8 bf =
            *(const short8*)(&Bb[cur][swz(nf * 16 + lr, ks * 64 + ls * 16)]);
        acc[nf] = mfma_bf16(af, bf, acc[nf]);
      }
    }
    __syncthreads();   // drains vmcnt (incl. next tile) + barrier
    cur ^= 1;
  }

  const int b = head >> 3, h = head & 7;
#pragma unroll
  for (int r = 0; r < 4; ++r) {
    int n = n0 + w * 16 + ls * 4 + r;
    float lv = lsum_g[(size_t)head * 1024 + n];
    float rinv = (lv > 0.f) ? 1.f / lv : 0.f;
#pragma unroll
    for (int nf = 0; nf < 4; ++nf)
      V1[((size_t)b * 1024 + n) * 512 + h * 64 + nf * 16 + lr] =
          acc[nf][r] * rinv;
  }
}

// ---------------------------------------------------------------------------
// Fused LayerNorm + swizzled transpose (layers 0/1)
// ---------------------------------------------------------------------------
__global__ __launch_bounds__(256) void k_ln_t(
    const float* __restrict__ V1, const float* __restrict__ Vf_in,
    const float* __restrict__ gamma, const float* __restrict__ beta,
    float* __restrict__ Vf_out, unsigned short* __restrict__ Vt) {
  __shared__ unsigned short tile[16 * 520];
  const int blk = blockIdx.x;
  const int b  = blk >> 6;
  const int n0 = (blk & 63) * 16;
  const int t = threadIdx.x;
  const int row = t >> 4;
  const int c0  = (t & 15) * 32;
  const size_t base = ((size_t)b * 1024 + n0 + row) * 512 + c0;

  float x[32];
  float s = 0.f, sq = 0.f;
#pragma unroll
  for (int j = 0; j < 32; j += 4) {
    float4 a = *(const float4*)(V1 + base + j);
    float4 v = *(const float4*)(Vf_in + base + j);
    float4 y = {a.x + v.x, a.y + v.y, a.z + v.z, a.w + v.w};
    x[j + 0] = y.x; x[j + 1] = y.y; x[j + 2] = y.z; x[j + 3] = y.w;
    s  += y.x + y.y + y.z + y.w;
    sq += y.x * y.x + y.y * y.y + y.z * y.z + y.w * y.w;
  }
#pragma unroll
  for (int off = 1; off < 16; off <<= 1) {
    s  += __shfl_xor(s, off, 64);
    sq += __shfl_xor(sq, off, 64);
  }
  float mu   = s * (1.f / 512.f);
  float var  = sq * (1.f / 512.f) - mu * mu;
  float rstd = rsqrtf(var + 1e-5f);

  unsigned short* trow = tile + row * 520 + c0;
#pragma unroll
  for (int j = 0; j < 32; j += 4) {
    float4 g = *(const float4*)(gamma + c0 + j);
    float4 bb = *(const float4*)(beta + c0 + j);
    float4 y;
    y.x = (x[j + 0] - mu) * rstd * g.x + bb.x;
    y.y = (x[j + 1] - mu) * rstd * g.y + bb.y;
    y.z = (x[j + 2] - mu) * rstd * g.z + bb.z;
    y.w = (x[j + 3] - mu) * rstd * g.w + bb.w;
    *(float4*)(Vf_out + base + j) = y;
    trow[j + 0] = f2bf(y.x); trow[j + 1] = f2bf(y.y);
    trow[j + 2] = f2bf(y.z); trow[j + 3] = f2bf(y.w);
  }
  __syncthreads();

#pragma unroll
  for (int it = 0; it < 2; ++it) {
    int d = t + it * 256;            // 0..511 (h*64+dh)
    int h = d >> 6, dh = d & 63;
    ushort8 o0, o1;
#pragma unroll
    for (int j = 0; j < 8; ++j) {
      o0[j] = tile[j * 520 + d];
      o1[j] = tile[(j + 8) * 520 + d];
    }
    int sw = (dh & 7) << 4;
    int byte0 = n0 * 2;                       // multiple of 32
    char* rowb = (char*)Vt + ((size_t)((b * 8 + h) * 64 + dh)) * 2048 +
                 (byte0 & ~127);
    *(ushort8*)(rowb + ((byte0 & 127) ^ sw)) = o0;
    *(ushort8*)(rowb + (((byte0 & 127) + 16) ^ sw)) = o1;
  }
}

// ---------------------------------------------------------------------------
// Plain LayerNorm (final layer -> d_out)
// ---------------------------------------------------------------------------
__global__ __launch_bounds__(256) void k_ln(
    const float* __restrict__ V1, const float* __restrict__ Vf_in,
    const float* __restrict__ gamma, const float* __restrict__ beta,
    float* __restrict__ outp) {
  const int row = blockIdx.x;
  const int t = threadIdx.x;
  const float* a = V1 + (size_t)row * 512;
  const float* b = Vf_in + (size_t)row * 512;
  float x0 = a[t] + b[t];
  float x1 = a[t + 256] + b[t + 256];
  float s  = x0 + x1;
  float sq = x0 * x0 + x1 * x1;
#pragma unroll
  for (int off = 32; off >= 1; off >>= 1) {
    s  += __shfl_down(s, off, 64);
    sq += __shfl_down(sq, off, 64);
  }
  __shared__ float red[8];
  int w = t >> 6, l = t & 63;
  if (l == 0) { red[w] = s; red[w + 4] = sq; }
  __syncthreads();
  s  = red[0] + red[1] + red[2] + red[3];
  sq = red[4] + red[5] + red[6] + red[7];
  float mu   = s * (1.f / 512.f);
  float var  = sq * (1.f / 512.f) - mu * mu;
  float rstd = rsqrtf(var + 1e-5f);
  float y0 = (x0 - mu) * rstd * gamma[t] + beta[t];
  float y1 = (x1 - mu) * rstd * gamma[t + 256] + beta[t + 256];
  outp[(size_t)row * 512 + t] = y0;
  outp[(size_t)row * 512 + t + 256] = y1;
}

// ---------------------------------------------------------------------------
// Fallback fused flash attention (ws < 103MB only; Vt is swizzled -> read
// at permuted position to fetch linear columns).
// ---------------------------------------------------------------------------
__global__ __launch_bounds__(256) void k_attn(
    const unsigned short* __restrict__ Qb,
    const unsigned short* __restrict__ Kb,
    const unsigned short* __restrict__ Vt,
    float* __restrict__ V1) {
  __shared__ char lds[8192 + 8192 + 4 * 16 * 144];
  char* kbuf = lds;
  char* vbuf = lds + 8192;
  const int bh = blockIdx.y;
  const int q0 = blockIdx.x * 64;
  const int t = threadIdx.x;
  const int w = t >> 6, l = t & 63, lr = l & 15, ls = l >> 4;
  char* pbuf = lds + 16384 + w * (16 * 144);

  const float scale = 0.044194173824159216f;

  short8 qa[2];
  {
    const unsigned short* Qg =
        Qb + ((size_t)bh * 1024 + q0 + w * 16 + lr) * 64 + ls * 8;
    qa[0] = *(const short8*)(Qg);
    qa[1] = *(const short8*)(Qg + 32);
  }

  f32x4 O[4] = {};
  float mrow[4], lrow[4];
#pragma unroll
  for (int r = 0; r < 4; ++r) { mrow[r] = -INFINITY; lrow[r] = 0.f; }

  const unsigned short* Kg = Kb + (size_t)bh * 1024 * 64;
  const char* Vg = (const char*)(Vt + (size_t)bh * 64 * 1024);

  for (int kc = 0; kc < 16; ++kc) {
    {
      int row = t >> 3;
      int c8  = (t & 7) * 8;
#pragma unroll
      for (int it = 0; it < 2; ++it) {
        int rr = row + it * 32;
        int4 kv = *(const int4*)(Kg + (size_t)(kc * 64 + rr) * 64 + c8);
        *(int4*)(kbuf + swz(rr, c8 * 2)) = kv;
        int swv = (rr & 7) << 4;
        int4 vv = *(const int4*)(Vg + (size_t)rr * 2048 + kc * 128 +
                                 ((c8 * 2) ^ swv));
        *(int4*)(vbuf + swz(rr, c8 * 2)) = vv;
      }
    }
    __syncthreads();

    f32x4 s[4] = {};
#pragma unroll
    for (int kk = 0; kk < 2; ++kk) {
#pragma unroll
      for (int nt = 0; nt < 4; ++nt) {
        short8 bk = *(const short8*)(kbuf + swz(nt * 16 + lr, kk * 64 + ls * 16));
        s[nt] = mfma_bf16(qa[kk], bk, s[nt]);
      }
    }

    float p[4][4];
    float cmax[4];
#pragma unroll
    for (int r = 0; r < 4; ++r) cmax[r] = -INFINITY;
#pragma unroll
    for (int nt = 0; nt < 4; ++nt)
#pragma unroll
      for (int r = 0; r < 4; ++r) {
        float sv = s[nt][r];
        p[nt][r] = (sv == 0.f) ? -INFINITY : sv * scale;
        cmax[r] = fmaxf(cmax[r], p[nt][r]);
      }
#pragma unroll
    for (int r = 0; r < 4; ++r)
#pragma unroll
      for (int off = 1; off < 16; off <<= 1)
        cmax[r] = fmaxf(cmax[r], __shfl_xor(cmax[r], off, 64));

    float alpha[4];
#pragma unroll
    for (int r = 0; r < 4; ++r) {
      float mnew = fmaxf(mrow[r], cmax[r]);
      alpha[r] = (mnew == -INFINITY) ? 1.f : exp2f((mrow[r] - mnew) * LOG2E);
      mrow[r] = mnew;
    }
    float lsum[4] = {0.f, 0.f, 0.f, 0.f};
#pragma unroll
    for (int nt = 0; nt < 4; ++nt)
#pragma unroll
      for (int r = 0; r < 4; ++r) {
        float pv = (p[nt][r] == -INFINITY)
                       ? 0.f
                       : exp2f((p[nt][r] - mrow[r]) * LOG2E);
        p[nt][r] = pv;
        lsum[r] += pv;
      }
#pragma unroll
    for (int r = 0; r < 4; ++r) {
#pragma unroll
      for (int off = 1; off < 16; off <<= 1)
        lsum[r] += __shfl_xor(lsum[r], off, 64);
      lrow[r] = lrow[r] * alpha[r] + lsum[r];
    }
#pragma unroll
    for (int dt = 0; dt < 4; ++dt)
#pragma unroll
      for (int r = 0; r < 4; ++r) O[dt][r] *= alpha[r];

#pragma unroll
    for (int nt = 0; nt < 4; ++nt)
#pragma unroll
      for (int r = 0; r < 4; ++r)
        *(unsigned short*)(pbuf + (ls * 4 + r) * 144 + (nt * 16 + lr) * 2) =
            f2bf(p[nt][r]);

#pragma unroll
    for (int kk = 0; kk < 2; ++kk) {
      short8 pa = *(const short8*)(pbuf + lr * 144 + kk * 64 + ls * 16);
#pragma unroll
      for (int dt = 0; dt < 4; ++dt) {
        short8 bv = *(const short8*)(vbuf + swz(dt * 16 + lr, kk * 64 + ls * 16));
        O[dt] = mfma_bf16(pa, bv, O[dt]);
      }
    }
    __syncthreads();
  }

  float rinv[4];
#pragma unroll
  for (int r = 0; r < 4; ++r) rinv[r] = (lrow[r] > 0.f) ? 1.f / lrow[r] : 0.f;
  const int b = bh >> 3, h = bh & 7;
#pragma unroll
  for (int dt = 0; dt < 4; ++dt)
#pragma unroll
    for (int r = 0; r < 4; ++r) {
      int n = q0 + w * 16 + ls * 4 + r;
      int c = h * 64 + dt * 16 + lr;
      V1[((size_t)b * 1024 + n) * 512 + c] = O[dt][r] * rinv[r];
    }
}

// ---------------------------------------------------------------------------
extern "C" void kernel_launch(void* const* d_in, const int* in_sizes, int n_in,
                              void* d_out, int out_size, void* d_ws,
                              size_t ws_size, hipStream_t stream) {
  const float* x1    = (const float*)d_in[0];
  const float* x2    = (const float*)d_in[1];
  const float* Wq    = (const float*)d_in[2];
  const float* Wk    = (const float*)d_in[3];
  const float* Wv    = (const float*)d_in[4];
  const float* gamma = (const float*)d_in[5];
  const float* beta  = (const float*)d_in[6];
  float* out = (float*)d_out;
  char* ws = (char*)d_ws;

  const size_t MB = 1u << 20;
  unsigned short* xb  = (unsigned short*)(ws);                 // 8 MB
  unsigned short* Wqb = (unsigned short*)(ws + 8 * MB);        // 0.5 MB
  unsigned short* Wkb = (unsigned short*)(ws + 8 * MB + 512 * 1024);
  unsigned short* Wvb = (unsigned short*)(ws + 9 * MB);        // 1 MB
  unsigned short* Qb  = (unsigned short*)(ws + 10 * MB);       // 4 MB
  unsigned short* Kb  = (unsigned short*)(ws + 14 * MB);       // 4 MB
  unsigned short* Vt  = (unsigned short*)(ws + 18 * MB);       // 4 MB
  float*          Vf  = (float*)(ws + 22 * MB);                // 8 MB
  float*          V1  = (float*)(ws + 30 * MB);                // 8 MB
  float*          lsm = (float*)(ws + 38 * MB);                // 128 KB
  unsigned short* Pm  = (unsigned short*)(ws + 39 * MB);       // 64 MB

  const bool bigws = ws_size >= (size_t)103 * MB;

  k_convert_x<<<2048, 256, 0, stream>>>(x1, x2, xb);
  k_convert<<<128, 256, 0, stream>>>(Wq, Wqb, 32768);
  k_convert<<<128, 256, 0, stream>>>(Wk, Wkb, 32768);
  k_convert<<<256, 256, 0, stream>>>(Wv, Wvb, 65536);

  k_proj<<<384, 256, 0, stream>>>(xb, Wqb, Wkb, Wvb, Qb, Kb, Vf);
  k_transpose_v<<<dim3(16, 32), 256, 0, stream>>>(Vf, Vt);

  if (bigws) {
    k_scores<<<512, 256, 0, stream>>>(Qb, Kb, Pm, lsm);
    for (int layer = 0; layer < 3; ++layer) {
      k_pv<<<512, 256, 0, stream>>>(Pm, Vt, lsm, V1);
      if (layer < 2)
        k_ln_t<<<256, 256, 0, stream>>>(V1, Vf, gamma, beta, Vf, Vt);
      else
        k_ln<<<4096, 256, 0, stream>>>(V1, Vf, gamma, beta, out);
    }
  } else {
    for (int layer = 0; layer < 3; ++layer) {
      k_attn<<<dim3(16, 32), 256, 0, stream>>>(Qb, Kb, Vt, V1);
      if (layer < 2) {
        k_ln_t<<<256, 256, 0, stream>>>(V1, Vf, gamma, beta, Vf, Vt);
      } else {
        k_ln<<<4096, 256, 0, stream>>>(V1, Vf, gamma, beta, out);
      }
    }
  }
}

// Round 9
// 145.689 us; speedup vs baseline: 1.6851x; 1.1491x over previous
//
#include <hip/hip_runtime.h>

// ---------------------------------------------------------------------------
// CrossModeAttention: B=4, N=1024, D1=D2=512, C=512, H=8, DH=64, LAYERS=3
// Q,K layer-invariant => P = exp(QK^T*scale) computed ONCE (bf16, 64MB,
// in-block-swizzled, coalesced); each layer = P·V GEMM + fused LN(+transpose).
// R9: k_scores/k_pv split 2x (1024 blocks) for occupancy; V1 in two halves.
// ---------------------------------------------------------------------------

#define LOG2E 1.44269504088896f

using f32x4   = __attribute__((ext_vector_type(4))) float;
using short8  = __attribute__((ext_vector_type(8))) short;
using ushort8 = __attribute__((ext_vector_type(8))) unsigned short;

__device__ inline unsigned short f2bf(float f) {
  unsigned u = __builtin_bit_cast(unsigned, f);
  u += 0x7fffu + ((u >> 16) & 1u);   // RNE
  return (unsigned short)(u >> 16);
}

__device__ inline f32x4 mfma_bf16(short8 a, short8 b, f32x4 c) {
  return __builtin_amdgcn_mfma_f32_16x16x32_bf16(a, b, c, 0, 0, 0);
}

__device__ inline void gload_lds16(const void* g, void* l) {
  __builtin_amdgcn_global_load_lds(
      (const __attribute__((address_space(1))) unsigned int*)g,
      (__attribute__((address_space(3))) unsigned int*)l, 16, 0, 0);
}

// XOR swizzle for 128B-row LDS tiles (G4)
__device__ inline int swz(int row, int byte_in_row) {
  return row * 128 + (byte_in_row ^ ((row & 7) << 4));
}

// ---------------------------------------------------------------------------
// Merged convert: xb bf16 [4096][1024] from x1|x2, then Wq,Wk,Wv -> bf16.
// One thread = 8 elements. Total 655360 threads -> grid 2560.
// ---------------------------------------------------------------------------
__global__ __launch_bounds__(256) void k_convert_all(
    const float* __restrict__ x1, const float* __restrict__ x2,
    const float* __restrict__ Wq, const float* __restrict__ Wk,
    const float* __restrict__ Wv,
    unsigned short* __restrict__ xb, unsigned short* __restrict__ Wqb,
    unsigned short* __restrict__ Wkb, unsigned short* __restrict__ Wvb) {
  int i = blockIdx.x * 256 + threadIdx.x;
  const float* src;
  unsigned short* dst;
  if (i < 524288) {                       // xb
    int e0 = i * 8, m = e0 >> 10, d = e0 & 1023;
    src = (d < 512) ? (x1 + (size_t)m * 512 + d)
                    : (x2 + (size_t)m * 512 + (d - 512));
    dst = xb + (size_t)e0;
  } else if (i < 557056) {                // Wq
    int j = (i - 524288) * 8;
    src = Wq + j; dst = Wqb + j;
  } else if (i < 589824) {                // Wk
    int j = (i - 557056) * 8;
    src = Wk + j; dst = Wkb + j;
  } else {                                // Wv
    int j = (i - 589824) * 8;
    src = Wv + j; dst = Wvb + j;
  }
  float4 a = ((const float4*)src)[0];
  float4 b = ((const float4*)src)[1];
  ushort8 o;
  o[0] = f2bf(a.x); o[1] = f2bf(a.y); o[2] = f2bf(a.z); o[3] = f2bf(a.w);
  o[4] = f2bf(b.x); o[5] = f2bf(b.y); o[6] = f2bf(b.z); o[7] = f2bf(b.w);
  *(ushort8*)dst = o;
}

// ---------------------------------------------------------------------------
// Projections: m97-structure GEMM. 128x128 tile, BK=64, global_load_lds.
// z=0 Q (K=512), z=1 K (K=512), z=2 V (K=1024).
// ---------------------------------------------------------------------------
__global__ __launch_bounds__(256) void k_proj(
    const unsigned short* __restrict__ xb,
    const unsigned short* __restrict__ Wqb,
    const unsigned short* __restrict__ Wkb,
    const unsigned short* __restrict__ Wvb,
    unsigned short* __restrict__ Qb, unsigned short* __restrict__ Kb,
    float* __restrict__ Vf) {
  __shared__ __align__(16) unsigned short Atile[128 * 64];
  __shared__ __align__(16) unsigned short Btile[128 * 64];

  const int id  = blockIdx.x;
  const int z   = id % 3;
  const int rem = id / 3;
  const int c0  = (rem & 3) * 128;
  const int m0  = (rem >> 2) * 128;

  const int K    = (z == 2) ? 1024 : 512;
  const int aoff = (z == 1) ? 512 : 0;
  const unsigned short* W = (z == 0) ? Wqb : (z == 1) ? Wkb : Wvb;

  const int t  = threadIdx.x;
  const int w  = t >> 6, l = t & 63;
  const int lr = l & 15, ls = l >> 4;
  const int wr = w >> 1, wc = w & 1;

  const int srow  = l >> 3;
  const int scol8 = (l & 7) * 8;

  f32x4 acc[4][4] = {};

  for (int k0 = 0; k0 < K; k0 += 64) {
#pragma unroll
    for (int j = 0; j < 4; ++j) {
      int ch  = w * 4 + j;
      int row = ch * 8 + srow;
      gload_lds16(xb + (size_t)(m0 + row) * 1024 + aoff + k0 + scol8,
                  Atile + ch * 512);
      gload_lds16(W + (size_t)(c0 + row) * K + k0 + scol8,
                  Btile + ch * 512);
    }
    __syncthreads();
#pragma unroll
    for (int ks = 0; ks < 2; ++ks) {
      short8 af[4], bf[4];
#pragma unroll
      for (int mf = 0; mf < 4; ++mf)
        af[mf] = *(const short8*)(Atile + (wr * 64 + mf * 16 + lr) * 64 +
                                  ks * 32 + ls * 8);
#pragma unroll
      for (int nf = 0; nf < 4; ++nf)
        bf[nf] = *(const short8*)(Btile + (wc * 64 + nf * 16 + lr) * 64 +
                                  ks * 32 + ls * 8);
#pragma unroll
      for (int mf = 0; mf < 4; ++mf)
#pragma unroll
        for (int nf = 0; nf < 4; ++nf)
          acc[mf][nf] = mfma_bf16(af[mf], bf[nf], acc[mf][nf]);
    }
    __syncthreads();
  }

#pragma unroll
  for (int mf = 0; mf < 4; ++mf)
#pragma unroll
    for (int nf = 0; nf < 4; ++nf)
#pragma unroll
      for (int r = 0; r < 4; ++r) {
        int m = m0 + wr * 64 + mf * 16 + ls * 4 + r;
        int c = c0 + wc * 64 + nf * 16 + lr;
        float v = acc[mf][nf][r];
        if (z == 2) {
          Vf[(size_t)m * 512 + c] = v;
        } else {
          int b = m >> 10, n = m & 1023, h = c >> 6, dh = c & 63;
          size_t idx = ((size_t)(b * 8 + h) * 1024 + n) * 64 + dh;
          (z == 0 ? Qb : Kb)[idx] = f2bf(v);
        }
      }
}

// ---------------------------------------------------------------------------
// Transpose (initial): Vf f32 [B,N,512] -> Vt bf16 [B,H,64,N], swizzled
// in-block (byte ^= (dh&7)<<4 within each 128B n-segment).
// ---------------------------------------------------------------------------
__global__ __launch_bounds__(256) void k_transpose_v(
    const float* __restrict__ Vf, unsigned short* __restrict__ Vt) {
  __shared__ unsigned short tile[64 * 66];
  const int bh = blockIdx.y;
  const int b = bh >> 3, h = bh & 7;
  const int n0 = blockIdx.x * 64;
  const int t = threadIdx.x;
  {
    int n = t >> 2, dh0 = (t & 3) * 16;
    const float* src = Vf + ((size_t)b * 1024 + n0 + n) * 512 + h * 64 + dh0;
    unsigned short* dst = tile + n * 66 + dh0;
#pragma unroll
    for (int j = 0; j < 16; j += 4) {
      float4 v = *(const float4*)(src + j);
      dst[j + 0] = f2bf(v.x); dst[j + 1] = f2bf(v.y);
      dst[j + 2] = f2bf(v.z); dst[j + 3] = f2bf(v.w);
    }
  }
  __syncthreads();
#pragma unroll
  for (int it = 0; it < 2; ++it) {
    int dh = (t >> 3) + it * 32, n8 = (t & 7) * 8;
    ushort8 o;
#pragma unroll
    for (int j = 0; j < 8; ++j) o[j] = tile[(n8 + j) * 66 + dh];
    char* dst = (char*)Vt + ((size_t)(bh * 64 + dh)) * 2048 + n0 * 2 +
                ((n8 * 2) ^ ((dh & 7) << 4));
    *(ushort8*)dst = o;
  }
}

// ---------------------------------------------------------------------------
// k_scores: P = exp(QK^T*scale), masked (s==0 -> 0). Grid 1024 XCD-chunked:
// head = lid>>5, qtile = (lid>>1)&15, khalf = lid&1 (8 kc-chunks each).
// Partial row sums -> lsm[khalf][32][1024].
// ---------------------------------------------------------------------------
__global__ __launch_bounds__(256) void k_scores(
    const unsigned short* __restrict__ Qb,
    const unsigned short* __restrict__ Kb,
    unsigned short* __restrict__ Pmat, float* __restrict__ lsum_g) {
  __shared__ char lds[8192 + 4 * 16 * 144];
  char* kbuf = lds;
  const int id  = blockIdx.x;
  const int lid = (id & 7) * 128 + (id >> 3);
  const int bh  = lid >> 5;
  const int q0  = ((lid >> 1) & 15) * 64;
  const int kh  = lid & 1;
  const int t = threadIdx.x;
  const int w = t >> 6, l = t & 63, lr = l & 15, ls = l >> 4;
  char* pbuf = lds + 8192 + w * (16 * 144);

  const float sclog2e = 0.0637587160f;   // (512^-0.5) * log2(e)

  short8 qa[2];
  {
    const unsigned short* Qg =
        Qb + ((size_t)bh * 1024 + q0 + w * 16 + lr) * 64 + ls * 8;
    qa[0] = *(const short8*)(Qg);
    qa[1] = *(const short8*)(Qg + 32);
  }

  const unsigned short* Kg = Kb + (size_t)bh * 1024 * 64 + kh * 512 * 64;
  char* Pg = (char*)(Pmat + (size_t)bh * 1024 * 1024);

  float lacc[4] = {0.f, 0.f, 0.f, 0.f};

  const int srow = t >> 3, sc8 = (t & 7) * 8;
  int4 kreg[2];
  kreg[0] = *(const int4*)(Kg + (size_t)(srow)*64 + sc8);
  kreg[1] = *(const int4*)(Kg + (size_t)(srow + 32) * 64 + sc8);

  for (int kc = 0; kc < 8; ++kc) {
    *(int4*)(kbuf + swz(srow, sc8 * 2)) = kreg[0];
    *(int4*)(kbuf + swz(srow + 32, sc8 * 2)) = kreg[1];
    __syncthreads();
    if (kc < 7) {   // T14: issue next K-chunk loads before compute
      kreg[0] = *(const int4*)(Kg + (size_t)((kc + 1) * 64 + srow) * 64 + sc8);
      kreg[1] = *(const int4*)(Kg + (size_t)((kc + 1) * 64 + srow + 32) * 64 + sc8);
    }

    f32x4 s[4] = {};
#pragma unroll
    for (int kk = 0; kk < 2; ++kk) {
#pragma unroll
      for (int nt = 0; nt < 4; ++nt) {
        short8 bk = *(const short8*)(kbuf + swz(nt * 16 + lr, kk * 64 + ls * 16));
        s[nt] = mfma_bf16(qa[kk], bk, s[nt]);
      }
    }

#pragma unroll
    for (int nt = 0; nt < 4; ++nt)
#pragma unroll
      for (int r = 0; r < 4; ++r) {
        float sv = s[nt][r];
        float pv = (sv == 0.f) ? 0.f : exp2f(sv * sclog2e);
        lacc[r] += pv;
        *(unsigned short*)(pbuf + (ls * 4 + r) * 144 + (nt * 16 + lr) * 2) =
            f2bf(pv);
      }

    // coalesced swizzled write: 8 lanes cover one full 128B row segment
    int gkc = kh * 8 + kc;
#pragma unroll
    for (int half = 0; half < 2; ++half) {
      int flat = l + half * 64;
      int prow = flat >> 3;
      int pchk = flat & 7;
      ushort8 pv8 = *(const ushort8*)(pbuf + prow * 144 + pchk * 16);
      int n = q0 + w * 16 + prow;
      *(ushort8*)(Pg + (size_t)n * 2048 + gkc * 128 +
                  ((pchk * 16) ^ ((n & 7) << 4))) = pv8;
    }
    __syncthreads();
  }

#pragma unroll
  for (int r = 0; r < 4; ++r) {
#pragma unroll
    for (int off = 1; off < 16; off <<= 1)
      lacc[r] += __shfl_xor(lacc[r], off, 64);
  }
  if (lr == 0) {
#pragma unroll
    for (int r = 0; r < 4; ++r)
      lsum_g[kh * 32768 + (size_t)bh * 1024 + q0 + w * 16 + ls * 4 + r] =
          lacc[r];
  }
}

// ---------------------------------------------------------------------------
// k_pv: V1h[n, h*64+dh] = (1/l[n]) * sum_{m in half} P[n,m] * Vt[h][dh][m].
// Grid 1024 XCD-chunked: head = lid>>5, ntile = (lid>>1)&15, mhalf = lid&1.
// gload_lds staging (pre-swizzled P and Vt), 2-phase double buffer.
// ---------------------------------------------------------------------------
__global__ __launch_bounds__(256) void k_pv(
    const unsigned short* __restrict__ Pmat,
    const unsigned short* __restrict__ Vt,
    const float* __restrict__ lsum_g, float* __restrict__ V1a,
    float* __restrict__ V1b) {
  __shared__ __align__(16) char Ab[2][8192];
  __shared__ __align__(16) char Bb[2][8192];
  const int id  = blockIdx.x;
  const int lid = (id & 7) * 128 + (id >> 3);
  const int head = lid >> 5;
  const int n0   = ((lid >> 1) & 15) * 64;
  const int mh   = lid & 1;
  const int t = threadIdx.x;
  const int w = t >> 6, l = t & 63, lr = l & 15, ls = l >> 4;

  const char* Pg = (const char*)(Pmat + (size_t)head * 1024 * 1024) +
                   (size_t)n0 * 2048 + mh * 1024;
  const char* Vg = (const char*)(Vt + (size_t)head * 64 * 1024) + mh * 1024;

  const int srow = w * 16 + (l >> 3);
  const int sc16 = (l & 7) * 16;

  f32x4 acc[4] = {};

  auto STAGE = [&](int buf, int kc) {
#pragma unroll
    for (int j = 0; j < 2; ++j) {
      int row = srow + j * 8;
      gload_lds16(Pg + (size_t)row * 2048 + kc * 128 + sc16,
                  &Ab[buf][w * 2048 + j * 1024]);
      gload_lds16(Vg + (size_t)row * 2048 + kc * 128 + sc16,
                  &Bb[buf][w * 2048 + j * 1024]);
    }
  };

  STAGE(0, 0);
  __syncthreads();
  int cur = 0;
  for (int kc = 0; kc < 8; ++kc) {
    if (kc < 7) STAGE(cur ^ 1, kc + 1);
#pragma unroll
    for (int ks = 0; ks < 2; ++ks) {
      short8 af = *(const short8*)(&Ab[cur][swz(w * 16 + lr, ks * 64 + ls * 16)]);
#pragma unroll
      for (int nf = 0; nf < 4; ++nf) {
        short8 bf =
            *(const short8*)(&Bb[cur][swz(nf * 16 + lr, ks * 64 + ls * 16)]);
        acc[nf] = mfma_bf16(af, bf, acc[nf]);
      }
    }
    __syncthreads();
    cur ^= 1;
  }

  float* V1 = mh ? V1b : V1a;
  const int b = head >> 3, h = head & 7;
#pragma unroll
  for (int r = 0; r < 4; ++r) {
    int n = n0 + w * 16 + ls * 4 + r;
    float lv = lsum_g[(size_t)head * 1024 + n] +
               lsum_g[32768 + (size_t)head * 1024 + n];
    float rinv = (lv > 0.f) ? 1.f / lv : 0.f;
#pragma unroll
    for (int nf = 0; nf < 4; ++nf)
      V1[((size_t)b * 1024 + n) * 512 + h * 64 + nf * 16 + lr] =
          acc[nf][r] * rinv;
  }
}

// ---------------------------------------------------------------------------
// Fused LayerNorm + swizzled transpose (layers 0/1): LN(V1a+V1b+Vf)
// ---------------------------------------------------------------------------
__global__ __launch_bounds__(256) void k_ln_t(
    const float* __restrict__ V1a, const float* __restrict__ V1b,
    const float* __restrict__ Vf_in,
    const float* __restrict__ gamma, const float* __restrict__ beta,
    float* __restrict__ Vf_out, unsigned short* __restrict__ Vt) {
  __shared__ unsigned short tile[16 * 520];
  const int blk = blockIdx.x;
  const int b  = blk >> 6;
  const int n0 = (blk & 63) * 16;
  const int t = threadIdx.x;
  const int row = t >> 4;
  const int c0  = (t & 15) * 32;
  const size_t base = ((size_t)b * 1024 + n0 + row) * 512 + c0;

  float x[32];
  float s = 0.f, sq = 0.f;
#pragma unroll
  for (int j = 0; j < 32; j += 4) {
    float4 a0 = *(const float4*)(V1a + base + j);
    float4 a1 = *(const float4*)(V1b + base + j);
    float4 v = *(const float4*)(Vf_in + base + j);
    float4 y = {a0.x + a1.x + v.x, a0.y + a1.y + v.y, a0.z + a1.z + v.z,
                a0.w + a1.w + v.w};
    x[j + 0] = y.x; x[j + 1] = y.y; x[j + 2] = y.z; x[j + 3] = y.w;
    s  += y.x + y.y + y.z + y.w;
    sq += y.x * y.x + y.y * y.y + y.z * y.z + y.w * y.w;
  }
#pragma unroll
  for (int off = 1; off < 16; off <<= 1) {
    s  += __shfl_xor(s, off, 64);
    sq += __shfl_xor(sq, off, 64);
  }
  float mu   = s * (1.f / 512.f);
  float var  = sq * (1.f / 512.f) - mu * mu;
  float rstd = rsqrtf(var + 1e-5f);

  unsigned short* trow = tile + row * 520 + c0;
#pragma unroll
  for (int j = 0; j < 32; j += 4) {
    float4 g = *(const float4*)(gamma + c0 + j);
    float4 bb = *(const float4*)(beta + c0 + j);
    float4 y;
    y.x = (x[j + 0] - mu) * rstd * g.x + bb.x;
    y.y = (x[j + 1] - mu) * rstd * g.y + bb.y;
    y.z = (x[j + 2] - mu) * rstd * g.z + bb.z;
    y.w = (x[j + 3] - mu) * rstd * g.w + bb.w;
    *(float4*)(Vf_out + base + j) = y;
    trow[j + 0] = f2bf(y.x); trow[j + 1] = f2bf(y.y);
    trow[j + 2] = f2bf(y.z); trow[j + 3] = f2bf(y.w);
  }
  __syncthreads();

#pragma unroll
  for (int it = 0; it < 2; ++it) {
    int d = t + it * 256;
    int h = d >> 6, dh = d & 63;
    ushort8 o0, o1;
#pragma unroll
    for (int j = 0; j < 8; ++j) {
      o0[j] = tile[j * 520 + d];
      o1[j] = tile[(j + 8) * 520 + d];
    }
    int sw = (dh & 7) << 4;
    int byte0 = n0 * 2;
    char* rowb = (char*)Vt + ((size_t)((b * 8 + h) * 64 + dh)) * 2048 +
                 (byte0 & ~127);
    *(ushort8*)(rowb + ((byte0 & 127) ^ sw)) = o0;
    *(ushort8*)(rowb + (((byte0 & 127) + 16) ^ sw)) = o1;
  }
}

// ---------------------------------------------------------------------------
// Plain LayerNorm (final layer -> d_out): LN(V1a+V1b+Vf)
// ---------------------------------------------------------------------------
__global__ __launch_bounds__(256) void k_ln(
    const float* __restrict__ V1a, const float* __restrict__ V1b,
    const float* __restrict__ Vf_in,
    const float* __restrict__ gamma, const float* __restrict__ beta,
    float* __restrict__ outp) {
  const int row = blockIdx.x;
  const int t = threadIdx.x;
  const float* a0 = V1a + (size_t)row * 512;
  const float* a1 = V1b + (size_t)row * 512;
  const float* b = Vf_in + (size_t)row * 512;
  float x0 = a0[t] + a1[t] + b[t];
  float x1 = a0[t + 256] + a1[t + 256] + b[t + 256];
  float s  = x0 + x1;
  float sq = x0 * x0 + x1 * x1;
#pragma unroll
  for (int off = 32; off >= 1; off >>= 1) {
    s  += __shfl_down(s, off, 64);
    sq += __shfl_down(sq, off, 64);
  }
  __shared__ float red[8];
  int w = t >> 6, l = t & 63;
  if (l == 0) { red[w] = s; red[w + 4] = sq; }
  __syncthreads();
  s  = red[0] + red[1] + red[2] + red[3];
  sq = red[4] + red[5] + red[6] + red[7];
  float mu   = s * (1.f / 512.f);
  float var  = sq * (1.f / 512.f) - mu * mu;
  float rstd = rsqrtf(var + 1e-5f);
  float y0 = (x0 - mu) * rstd * gamma[t] + beta[t];
  float y1 = (x1 - mu) * rstd * gamma[t + 256] + beta[t + 256];
  outp[(size_t)row * 512 + t] = y0;
  outp[(size_t)row * 512 + t + 256] = y1;
}

// ---------------------------------------------------------------------------
// Fallback fused flash attention (ws < 103MB only; Vt swizzled)
// ---------------------------------------------------------------------------
__global__ __launch_bounds__(256) void k_attn(
    const unsigned short* __restrict__ Qb,
    const unsigned short* __restrict__ Kb,
    const unsigned short* __restrict__ Vt,
    float* __restrict__ V1) {
  __shared__ char lds[8192 + 8192 + 4 * 16 * 144];
  char* kbuf = lds;
  char* vbuf = lds + 8192;
  const int bh = blockIdx.y;
  const int q0 = blockIdx.x * 64;
  const int t = threadIdx.x;
  const int w = t >> 6, l = t & 63, lr = l & 15, ls = l >> 4;
  char* pbuf = lds + 16384 + w * (16 * 144);

  const float scale = 0.044194173824159216f;

  short8 qa[2];
  {
    const unsigned short* Qg =
        Qb + ((size_t)bh * 1024 + q0 + w * 16 + lr) * 64 + ls * 8;
    qa[0] = *(const short8*)(Qg);
    qa[1] = *(const short8*)(Qg + 32);
  }

  f32x4 O[4] = {};
  float mrow[4], lrow[4];
#pragma unroll
  for (int r = 0; r < 4; ++r) { mrow[r] = -INFINITY; lrow[r] = 0.f; }

  const unsigned short* Kg = Kb + (size_t)bh * 1024 * 64;
  const char* Vg = (const char*)(Vt + (size_t)bh * 64 * 1024);

  for (int kc = 0; kc < 16; ++kc) {
    {
      int row = t >> 3;
      int c8  = (t & 7) * 8;
#pragma unroll
      for (int it = 0; it < 2; ++it) {
        int rr = row + it * 32;
        int4 kv = *(const int4*)(Kg + (size_t)(kc * 64 + rr) * 64 + c8);
        *(int4*)(kbuf + swz(rr, c8 * 2)) = kv;
        int swv = (rr & 7) << 4;
        int4 vv = *(const int4*)(Vg + (size_t)rr * 2048 + kc * 128 +
                                 ((c8 * 2) ^ swv));
        *(int4*)(vbuf + swz(rr, c8 * 2)) = vv;
      }
    }
    __syncthreads();

    f32x4 s[4] = {};
#pragma unroll
    for (int kk = 0; kk < 2; ++kk) {
#pragma unroll
      for (int nt = 0; nt < 4; ++nt) {
        short8 bk = *(const short8*)(kbuf + swz(nt * 16 + lr, kk * 64 + ls * 16));
        s[nt] = mfma_bf16(qa[kk], bk, s[nt]);
      }
    }

    float p[4][4];
    float cmax[4];
#pragma unroll
    for (int r = 0; r < 4; ++r) cmax[r] = -INFINITY;
#pragma unroll
    for (int nt = 0; nt < 4; ++nt)
#pragma unroll
      for (int r = 0; r < 4; ++r) {
        float sv = s[nt][r];
        p[nt][r] = (sv == 0.f) ? -INFINITY : sv * scale;
        cmax[r] = fmaxf(cmax[r], p[nt][r]);
      }
#pragma unroll
    for (int r = 0; r < 4; ++r)
#pragma unroll
      for (int off = 1; off < 16; off <<= 1)
        cmax[r] = fmaxf(cmax[r], __shfl_xor(cmax[r], off, 64));

    float alpha[4];
#pragma unroll
    for (int r = 0; r < 4; ++r) {
      float mnew = fmaxf(mrow[r], cmax[r]);
      alpha[r] = (mnew == -INFINITY) ? 1.f : exp2f((mrow[r] - mnew) * LOG2E);
      mrow[r] = mnew;
    }
    float lsum[4] = {0.f, 0.f, 0.f, 0.f};
#pragma unroll
    for (int nt = 0; nt < 4; ++nt)
#pragma unroll
      for (int r = 0; r < 4; ++r) {
        float pv = (p[nt][r] == -INFINITY)
                       ? 0.f
                       : exp2f((p[nt][r] - mrow[r]) * LOG2E);
        p[nt][r] = pv;
        lsum[r] += pv;
      }
#pragma unroll
    for (int r = 0; r < 4; ++r) {
#pragma unroll
      for (int off = 1; off < 16; off <<= 1)
        lsum[r] += __shfl_xor(lsum[r], off, 64);
      lrow[r] = lrow[r] * alpha[r] + lsum[r];
    }
#pragma unroll
    for (int dt = 0; dt < 4; ++dt)
#pragma unroll
      for (int r = 0; r < 4; ++r) O[dt][r] *= alpha[r];

#pragma unroll
    for (int nt = 0; nt < 4; ++nt)
#pragma unroll
      for (int r = 0; r < 4; ++r)
        *(unsigned short*)(pbuf + (ls * 4 + r) * 144 + (nt * 16 + lr) * 2) =
            f2bf(p[nt][r]);

#pragma unroll
    for (int kk = 0; kk < 2; ++kk) {
      short8 pa = *(const short8*)(pbuf + lr * 144 + kk * 64 + ls * 16);
#pragma unroll
      for (int dt = 0; dt < 4; ++dt) {
        short8 bv = *(const short8*)(vbuf + swz(dt * 16 + lr, kk * 64 + ls * 16));
        O[dt] = mfma_bf16(pa, bv, O[dt]);
      }
    }
    __syncthreads();
  }

  float rinv[4];
#pragma unroll
  for (int r = 0; r < 4; ++r) rinv[r] = (lrow[r] > 0.f) ? 1.f / lrow[r] : 0.f;
  const int b = bh >> 3, h = bh & 7;
#pragma unroll
  for (int dt = 0; dt < 4; ++dt)
#pragma unroll
    for (int r = 0; r < 4; ++r) {
      int n = q0 + w * 16 + ls * 4 + r;
      int c = h * 64 + dt * 16 + lr;
      V1[((size_t)b * 1024 + n) * 512 + c] = O[dt][r] * rinv[r];
    }
}

// ---------------------------------------------------------------------------
extern "C" void kernel_launch(void* const* d_in, const int* in_sizes, int n_in,
                              void* d_out, int out_size, void* d_ws,
                              size_t ws_size, hipStream_t stream) {
  const float* x1    = (const float*)d_in[0];
  const float* x2    = (const float*)d_in[1];
  const float* Wq    = (const float*)d_in[2];
  const float* Wk    = (const float*)d_in[3];
  const float* Wv    = (const float*)d_in[4];
  const float* gamma = (const float*)d_in[5];
  const float* beta  = (const float*)d_in[6];
  float* out = (float*)d_out;
  char* ws = (char*)d_ws;

  const size_t MB = 1u << 20;
  unsigned short* xb  = (unsigned short*)(ws);                 // 8 MB (dead after proj)
  unsigned short* Wqb = (unsigned short*)(ws + 8 * MB);        // 0.5 MB
  unsigned short* Wkb = (unsigned short*)(ws + 8 * MB + 512 * 1024);
  unsigned short* Wvb = (unsigned short*)(ws + 9 * MB);        // 1 MB
  unsigned short* Qb  = (unsigned short*)(ws + 10 * MB);       // 4 MB
  unsigned short* Kb  = (unsigned short*)(ws + 14 * MB);       // 4 MB
  unsigned short* Vt  = (unsigned short*)(ws + 18 * MB);       // 4 MB
  float*          Vf  = (float*)(ws + 22 * MB);                // 8 MB
  float*          V1a = (float*)(ws + 30 * MB);                // 8 MB
  float*          lsm = (float*)(ws + 38 * MB);                // 256 KB
  unsigned short* Pm  = (unsigned short*)(ws + 39 * MB);       // 64 MB
  float*          V1b = (float*)(ws);                          // reuse xb region

  const bool bigws = ws_size >= (size_t)103 * MB;

  k_convert_all<<<2560, 256, 0, stream>>>(x1, x2, Wq, Wk, Wv, xb, Wqb, Wkb,
                                          Wvb);
  k_proj<<<384, 256, 0, stream>>>(xb, Wqb, Wkb, Wvb, Qb, Kb, Vf);
  k_transpose_v<<<dim3(16, 32), 256, 0, stream>>>(Vf, Vt);

  if (bigws) {
    k_scores<<<1024, 256, 0, stream>>>(Qb, Kb, Pm, lsm);
    for (int layer = 0; layer < 3; ++layer) {
      k_pv<<<1024, 256, 0, stream>>>(Pm, Vt, lsm, V1a, V1b);
      if (layer < 2)
        k_ln_t<<<256, 256, 0, stream>>>(V1a, V1b, Vf, gamma, beta, Vf, Vt);
      else
        k_ln<<<4096, 256, 0, stream>>>(V1a, V1b, Vf, gamma, beta, out);
    }
  } else {
    // fallback: single-buffer attention; V1b zeroed once (xb region is dead)
    hipMemsetAsync(V1b, 0, 8 * MB, stream);
    for (int layer = 0; layer < 3; ++layer) {
      k_attn<<<dim3(16, 32), 256, 0, stream>>>(Qb, Kb, Vt, V1a);
      if (layer < 2)
        k_ln_t<<<256, 256, 0, stream>>>(V1a, V1b, Vf, gamma, beta, Vf, Vt);
      else
        k_ln<<<4096, 256, 0, stream>>>(V1a, V1b, Vf, gamma, beta, out);
    }
  }
}